// Round 7
// baseline (437.338 us; speedup 1.0000x reference)
//
#include <hip/hip_runtime.h>

#define BB 4
#define NN 512
#define FIN 128
#define HH 4
#define DD 32
#define HID 128
#define NOUT 384   // 128 src + 128 tgt + 128 res
#define MT 8
#define LN_EPS 1e-5f
#define NEG 0.2f
#define SCALE 0.17677669529663687f

typedef __attribute__((ext_vector_type(8))) short bf16x8;
typedef __attribute__((ext_vector_type(4))) float f32x4;

__device__ __forceinline__ float leaky(float x){ return x > 0.f ? x : NEG*x; }

// round-to-nearest-even fp32 -> bf16 (finite inputs)
__device__ __forceinline__ unsigned f2bf(float f){
    unsigned u = __float_as_uint(f);
    return (u + 0x7fffu + ((u >> 16) & 1u)) >> 16;
}

// Pack Wt[k][o]: o in [0,128)=W_src rows, [128,256)=W_tgt rows, [256,384)=W_res rows
__global__ void pack_w(const float* __restrict__ Wsrc, const float* __restrict__ Wtgt,
                       const float* __restrict__ Wres, float* __restrict__ Wt) {
    int idx = blockIdx.x * 256 + threadIdx.x;
    if (idx >= FIN * NOUT) return;
    int k = idx / NOUT, o = idx % NOUT;
    float v;
    if (o < 128)      v = Wsrc[o * FIN + k];
    else if (o < 256) v = Wtgt[(o - 128) * FIN + k];
    else              v = Wres[(o - 256) * FIN + k];
    Wt[idx] = v;
}

// Fused proj: Linear -> LayerNorm(32) -> LeakyReLU for src/tgt, Linear+bias+Leaky for res.
// U_tgt emitted ONLY transposed: fp32 tTf[bh][d][n] + bf16 tT[bh][d][n].
__global__ __launch_bounds__(NOUT) void proj_kernel(
    const float* __restrict__ x, const float* __restrict__ Wt,
    const float* __restrict__ gsrc, const float* __restrict__ bsrc,
    const float* __restrict__ gtgt, const float* __restrict__ btgt,
    const float* __restrict__ bres,
    float* __restrict__ Usrc, float* __restrict__ res,
    float* __restrict__ tTf, unsigned short* __restrict__ tT)
{
    __shared__ float xs[MT * FIN];
    int tid = threadIdx.x;
    int r0 = blockIdx.x * MT;              // row over flattened [B*N]
    const float* base = x + (size_t)r0 * FIN;
    for (int idx = tid; idx < MT * FIN; idx += NOUT) xs[idx] = base[idx];
    __syncthreads();

    int o = tid;
    float acc[MT];
    #pragma unroll
    for (int m = 0; m < MT; m++) acc[m] = 0.f;
    for (int k = 0; k < FIN; k++) {
        float w = Wt[k * NOUT + o];
        #pragma unroll
        for (int m = 0; m < MT; m++) acc[m] = fmaf(w, xs[m * FIN + k], acc[m]);
    }

    float gg = 1.f, bb2 = 0.f, bres_v = 0.f;
    if (o < 128)      { gg = gsrc[o];       bb2 = bsrc[o]; }
    else if (o < 256) { gg = gtgt[o - 128]; bb2 = btgt[o - 128]; }
    else              { bres_v = bres[o - 256]; }

    float tf[MT];
    unsigned tpack[4];
    #pragma unroll
    for (int m = 0; m < MT; m++) {
        int r = r0 + m;
        int b = r >> 9;            // /512
        int n = r & (NN - 1);
        float v = acc[m];
        if (o < 256) {
            float s = v, sq = v * v;
            #pragma unroll
            for (int msk = 16; msk >= 1; msk >>= 1) {
                s  += __shfl_xor(s,  msk);
                sq += __shfl_xor(sq, msk);
            }
            float mean = s * (1.f / DD);
            float var  = sq * (1.f / DD) - mean * mean;
            float nv = (v - mean) * rsqrtf(var + LN_EPS);
            nv = leaky(nv * gg + bb2);
            int oo = o & 127;
            int hh = oo >> 5, d = oo & 31;
            if (o < 128) {
                Usrc[((size_t)(b * HH + hh) * NN + n) * DD + d] = nv;
            } else {
                tf[m] = nv;
                unsigned bf = f2bf(nv);
                if (m & 1) tpack[m >> 1] |= bf << 16; else tpack[m >> 1] = bf;
            }
        } else {
            res[(size_t)r * HID + (o - 256)] = leaky(v + bres_v);
        }
    }
    if (o >= 128 && o < 256) {
        int oo = o & 127, hh = oo >> 5, d = oo & 31;
        int b = r0 >> 9, n0 = r0 & (NN - 1);
        size_t off = ((size_t)(b * HH + hh) * DD + d) * NN + n0;   // n0 % 8 == 0
        *(float4*)(tTf + off)     = make_float4(tf[0], tf[1], tf[2], tf[3]);
        *(float4*)(tTf + off + 4) = make_float4(tf[4], tf[5], tf[6], tf[7]);
        *(uint4*)(tT + off) = make_uint4(tpack[0], tpack[1], tpack[2], tpack[3]);
    }
}

// e+softmax, templated for phase ablation. Real instance = <0,0,0,1>.
// SKIP_TLOAD: synthesize t (no global t reads). SKIP_ELOOP: acc opaque-zero.
// SKIP_SM: no exp/reduce/store (acc asm-consumed). REP: repeat count.
template<int SKIP_TLOAD, int SKIP_ELOOP, int SKIP_SM, int REP>
__global__ __launch_bounds__(512) void escore_v(
    const float* __restrict__ Usrc, const float* __restrict__ tTf,
    const float* __restrict__ attn, unsigned short* __restrict__ pOut)
{
    __shared__ float s_lds[8][DD];     // 1KB
    __shared__ float wsum[8][8];

    const int tid = threadIdx.x;
    const int blk = blockIdx.x;
    const int it = blk & 63;           // 64 i-tiles of 8 rows
    const int bh = blk >> 6;           // 0..15

    const float* tcol = tTf + (size_t)bh * DD * NN + tid;          // coalesced columns
    const float* srcU = Usrc + (size_t)bh * NN * DD + (size_t)(it * 8) * DD;

    // a hoisted into VGPRs once, made opaque (cannot be re-loaded in-loop)
    float areg[DD];
    {
        const float* aU = attn + (bh & 3) * DD;
        #pragma unroll
        for (int q = 0; q < 8; q++) {
            float4 v = *(const float4*)(aU + q * 4);
            areg[q*4+0] = v.x; areg[q*4+1] = v.y; areg[q*4+2] = v.z; areg[q*4+3] = v.w;
        }
        #pragma unroll
        for (int d = 0; d < DD; d++) asm volatile("" : "+v"(areg[d]));
    }
    if (tid < 64) ((float4*)s_lds)[tid] = ((const float4*)srcU)[tid];
    __syncthreads();

    for (int rep = 0; rep < REP; rep++) {
        float t[DD];
        if (!SKIP_TLOAD) {
            #pragma unroll
            for (int d = 0; d < DD; d++) t[d] = tcol[(size_t)d * NN];
        } else {
            #pragma unroll
            for (int d = 0; d < DD; d++) {
                t[d] = (float)((tid + d) & 31) * 0.01f;
                asm volatile("" : "+v"(t[d]));
            }
        }

        float At = 0.f, acc[8];
        #pragma unroll
        for (int r = 0; r < 8; r++) acc[r] = 0.f;

        if (!SKIP_ELOOP) {
            #pragma unroll
            for (int dg = 0; dg < 8; dg++) {
                const float a0 = areg[dg*4+0], a1 = areg[dg*4+1],
                            a2 = areg[dg*4+2], a3 = areg[dg*4+3];
                const float t0 = t[dg*4+0], t1 = t[dg*4+1],
                            t2 = t[dg*4+2], t3 = t[dg*4+3];
                At = fmaf(a0, t0, fmaf(a1, t1, fmaf(a2, t2, fmaf(a3, t3, At))));
                #pragma unroll
                for (int r = 0; r < 8; r++) {
                    float4 sv = *(float4*)&s_lds[r][dg * 4];
                    acc[r] = fmaf(a0, fabsf(sv.x + t0), acc[r]);
                    acc[r] = fmaf(a1, fabsf(sv.y + t1), acc[r]);
                    acc[r] = fmaf(a2, fabsf(sv.z + t2), acc[r]);
                    acc[r] = fmaf(a3, fabsf(sv.w + t3), acc[r]);
                }
            }
        } else {
            #pragma unroll
            for (int d = 0; d < DD; d++) asm volatile("" :: "v"(t[d]));   // consume t
            #pragma unroll
            for (int r = 0; r < 8; r++) asm volatile("" : "+v"(acc[r]));  // opaque acc
            asm volatile("" : "+v"(At));
        }

        if (!SKIP_SM) {
            const float cAt = 0.6f * SCALE * At;
            const int lane = tid & 63, w = tid >> 6;
            #pragma unroll
            for (int r = 0; r < 8; r++) {
                float p = __expf(fmaf(0.4f * SCALE, acc[r], cAt));
                acc[r] = p;
                float s = p;
                #pragma unroll
                for (int msk = 32; msk >= 1; msk >>= 1) s += __shfl_xor(s, msk);
                if (lane == 0) wsum[r][w] = s;
            }
            __syncthreads();
            unsigned short* pRow = pOut + ((size_t)bh * NN + it * 8) * NN + tid;
            #pragma unroll
            for (int r = 0; r < 8; r++) {
                float4 s0 = *(float4*)&wsum[r][0];
                float4 s1 = *(float4*)&wsum[r][4];
                float tot = ((s0.x + s0.y) + (s0.z + s0.w)) + ((s1.x + s1.y) + (s1.z + s1.w));
                pRow[(size_t)r * NN] = (unsigned short)f2bf(acc[r] / tot);
            }
            if (REP > 1) __syncthreads();          // wsum reuse across reps
        } else {
            #pragma unroll
            for (int r = 0; r < 8; r++) asm volatile("" :: "v"(acc[r]));  // anti-DCE
            asm volatile("" :: "v"(At));
        }
        if (REP > 1) asm volatile("" ::: "memory");  // no CSE across reps
    }
}

// agg: batched MFMA GEMM  out[bh] = p[bh] (512x512) @ tT[bh] (32x512, k-contig)
// + residual + ReLU. One wave per 16-row M-tile; both n-tiles (32 d) per wave.
__global__ __launch_bounds__(256) void agg_kernel(
    const unsigned short* __restrict__ pM, const unsigned short* __restrict__ tT,
    const float* __restrict__ res, float* __restrict__ out)
{
    const int tid = threadIdx.x, l = tid & 63;
    const int gw = blockIdx.x * 4 + (tid >> 6);   // 0..511
    const int bh = gw >> 5, mt = gw & 31;
    const int b = bh >> 2, h = bh & 3;

    const unsigned short* pA = pM + (size_t)bh * NN * NN
                               + (size_t)(mt * 16 + (l & 15)) * NN + ((l >> 4) * 8);
    const unsigned short* pB = tT + (size_t)bh * DD * NN
                               + (size_t)(l & 15) * NN + ((l >> 4) * 8);

    f32x4 acc0 = {0.f, 0.f, 0.f, 0.f}, acc1 = {0.f, 0.f, 0.f, 0.f};
    #pragma unroll
    for (int kt = 0; kt < 16; kt++) {
        bf16x8 av = *(const bf16x8*)(pA + kt * 32);
        bf16x8 b0 = *(const bf16x8*)(pB + kt * 32);
        bf16x8 b1 = *(const bf16x8*)(pB + 16 * NN + kt * 32);
        acc0 = __builtin_amdgcn_mfma_f32_16x16x32_bf16(av, b0, acc0, 0, 0, 0);
        acc1 = __builtin_amdgcn_mfma_f32_16x16x32_bf16(av, b1, acc1, 0, 0, 0);
    }

    // C/D layout (m89): col = lane&15, row = (lane>>4)*4 + reg
    const int i0 = mt * 16 + (l >> 4) * 4;
    const int cc = l & 15;
    #pragma unroll
    for (int q = 0; q < 4; q++) {
        size_t row = (size_t)b * NN + i0 + q;
        size_t a0 = row * HID + h * DD + cc;
        out[a0]      = fmaxf(acc0[q] + res[a0],      0.f);
        out[a0 + 16] = fmaxf(acc1[q] + res[a0 + 16], 0.f);
    }
}

extern "C" void kernel_launch(void* const* d_in, const int* in_sizes, int n_in,
                              void* d_out, int out_size, void* d_ws, size_t ws_size,
                              hipStream_t stream) {
    const float* uf   = (const float*)d_in[0];
    const float* Wsrc = (const float*)d_in[1];
    const float* gsrc = (const float*)d_in[2];
    const float* bsrc = (const float*)d_in[3];
    const float* Wtgt = (const float*)d_in[4];
    const float* gtgt = (const float*)d_in[5];
    const float* btgt = (const float*)d_in[6];
    const float* attn = (const float*)d_in[7];
    const float* Wres = (const float*)d_in[8];
    const float* bres = (const float*)d_in[9];
    float* out = (float*)d_out;

    float* ws   = (float*)d_ws;
    float* Wt   = ws;                        // 49152 f
    float* Usrc = ws + 49152;                // 262144 f
    float* resb = Usrc + 262144;             // 262144 f
    float* tTf  = resb + 262144;             // 262144 f (fp32 transposed U_tgt)
    unsigned short* tT = (unsigned short*)(tTf + 262144);    // 262144 u16
    unsigned short* pM = tT + 262144;                        // 16*512*512 u16 = 8 MB
    unsigned short* pDummy = pM + (size_t)16 * NN * NN;      // 8 MB ablation scratch

    pack_w<<<(FIN * NOUT + 255) / 256, 256, 0, stream>>>(Wsrc, Wtgt, Wres, Wt);
    proj_kernel<<<(BB * NN) / MT, NOUT, 0, stream>>>(uf, Wt, gsrc, bsrc, gtgt, btgt,
                                                     bres, Usrc, resb, tTf, tT);
    // ---- ablation variants (write pDummy, never read; REP=2 to outrank fills) ----
    escore_v<0,0,0,2><<<BB * HH * (NN / 8), 512, 0, stream>>>(Usrc, tTf, attn, pDummy); // V_full
    escore_v<0,0,1,2><<<BB * HH * (NN / 8), 512, 0, stream>>>(Usrc, tTf, attn, pDummy); // V_noSM
    escore_v<0,1,0,2><<<BB * HH * (NN / 8), 512, 0, stream>>>(Usrc, tTf, attn, pDummy); // V_noE
    escore_v<1,0,0,2><<<BB * HH * (NN / 8), 512, 0, stream>>>(Usrc, tTf, attn, pDummy); // V_noT
    // ---- real pipeline ----
    escore_v<0,0,0,1><<<BB * HH * (NN / 8), 512, 0, stream>>>(Usrc, tTf, attn, pM);
    agg_kernel<<<128, 256, 0, stream>>>(pM, tT, resb, out);
}

// Round 8
// 62.451 us; speedup vs baseline: 7.0030x; 7.0030x over previous
//
#include <hip/hip_runtime.h>

#define BB 4
#define NN 512
#define FIN 128
#define HH 4
#define DD 32
#define HID 128
#define NOUT 384   // 128 src + 128 tgt + 128 res
#define MT 8
#define LN_EPS 1e-5f
#define NEG 0.2f
#define SCALE 0.17677669529663687f

typedef __attribute__((ext_vector_type(8))) short bf16x8;
typedef __attribute__((ext_vector_type(4))) float f32x4;

__device__ __forceinline__ float leaky(float x){ return x > 0.f ? x : NEG*x; }

// round-to-nearest-even fp32 -> bf16 (finite inputs)
__device__ __forceinline__ unsigned f2bf(float f){
    unsigned u = __float_as_uint(f);
    return (u + 0x7fffu + ((u >> 16) & 1u)) >> 16;
}
__device__ __forceinline__ float bflo(unsigned u){ return __uint_as_float(u << 16); }
__device__ __forceinline__ float bfhi(unsigned u){ return __uint_as_float(u & 0xffff0000u); }

// Pack Wt[k][o]: o in [0,128)=W_src rows, [128,256)=W_tgt rows, [256,384)=W_res rows
__global__ void pack_w(const float* __restrict__ Wsrc, const float* __restrict__ Wtgt,
                       const float* __restrict__ Wres, float* __restrict__ Wt) {
    int idx = blockIdx.x * 256 + threadIdx.x;
    if (idx >= FIN * NOUT) return;
    int k = idx / NOUT, o = idx % NOUT;
    float v;
    if (o < 128)      v = Wsrc[o * FIN + k];
    else if (o < 256) v = Wtgt[(o - 128) * FIN + k];
    else              v = Wres[(o - 256) * FIN + k];
    Wt[idx] = v;
}

// Fused proj: Linear -> LayerNorm(32) -> LeakyReLU for src/tgt, Linear+bias+Leaky for res.
// U_tgt emitted ONLY as bf16, twice: tT[bh][d][n] (agg B-operand, n-pairs) and
// tP[bh][d2][n] (escore t-columns, d-pairs packed in u32).
__global__ __launch_bounds__(NOUT) void proj_kernel(
    const float* __restrict__ x, const float* __restrict__ Wt,
    const float* __restrict__ gsrc, const float* __restrict__ bsrc,
    const float* __restrict__ gtgt, const float* __restrict__ btgt,
    const float* __restrict__ bres,
    float* __restrict__ Usrc, float* __restrict__ res,
    unsigned short* __restrict__ tT, unsigned* __restrict__ tP)
{
    __shared__ float xs[MT * FIN];
    int tid = threadIdx.x;
    int r0 = blockIdx.x * MT;              // row over flattened [B*N]
    const float* base = x + (size_t)r0 * FIN;
    for (int idx = tid; idx < MT * FIN; idx += NOUT) xs[idx] = base[idx];
    __syncthreads();

    int o = tid;
    float acc[MT];
    #pragma unroll
    for (int m = 0; m < MT; m++) acc[m] = 0.f;
    for (int k = 0; k < FIN; k++) {
        float w = Wt[k * NOUT + o];
        #pragma unroll
        for (int m = 0; m < MT; m++) acc[m] = fmaf(w, xs[m * FIN + k], acc[m]);
    }

    float gg = 1.f, bb2 = 0.f, bres_v = 0.f;
    if (o < 128)      { gg = gsrc[o];       bb2 = bsrc[o]; }
    else if (o < 256) { gg = gtgt[o - 128]; bb2 = btgt[o - 128]; }
    else              { bres_v = bres[o - 256]; }

    unsigned bfall[MT];
    unsigned tpack[4];
    #pragma unroll
    for (int m = 0; m < MT; m++) {
        int r = r0 + m;
        int b = r >> 9;            // /512
        int n = r & (NN - 1);
        float v = acc[m];
        if (o < 256) {
            float s = v, sq = v * v;
            #pragma unroll
            for (int msk = 16; msk >= 1; msk >>= 1) {
                s  += __shfl_xor(s,  msk);
                sq += __shfl_xor(sq, msk);
            }
            float mean = s * (1.f / DD);
            float var  = sq * (1.f / DD) - mean * mean;
            float nv = (v - mean) * rsqrtf(var + LN_EPS);
            nv = leaky(nv * gg + bb2);
            int oo = o & 127;
            int hh = oo >> 5, d = oo & 31;
            if (o < 128) {
                Usrc[((size_t)(b * HH + hh) * NN + n) * DD + d] = nv;
            } else {
                unsigned bf = f2bf(nv);
                bfall[m] = bf;
                if (m & 1) tpack[m >> 1] |= bf << 16; else tpack[m >> 1] = bf;
            }
        } else {
            res[(size_t)r * HID + (o - 256)] = leaky(v + bres_v);
        }
    }
    if (o >= 128 && o < 256) {
        int oo = o & 127, hh = oo >> 5, d = oo & 31;
        int b = r0 >> 9, n0 = r0 & (NN - 1);
        size_t off = ((size_t)(b * HH + hh) * DD + d) * NN + n0;   // n0 % 8 == 0
        *(uint4*)(tT + off) = make_uint4(tpack[0], tpack[1], tpack[2], tpack[3]);
        // d-pair packing for escore: lanes d, d^1 are adjacent in the wave
        unsigned pd[MT];
        #pragma unroll
        for (int m = 0; m < MT; m++) {
            unsigned prt = (unsigned)__shfl_xor((int)bfall[m], 1);
            pd[m] = bfall[m] | (prt << 16);          // valid on even-d lanes
        }
        if ((d & 1) == 0) {
            size_t offp = ((size_t)(b * HH + hh) * 16 + (d >> 1)) * NN + n0;
            *(uint4*)(tP + offp)     = make_uint4(pd[0], pd[1], pd[2], pd[3]);
            *(uint4*)(tP + offp + 4) = make_uint4(pd[4], pd[5], pd[6], pd[7]);
        }
    }
}

// e+softmax kernel: one block per (b,h, 8-row i-tile); thread owns one t column,
// held as 16 packed bf16x2 u32 regs (register-lean, no spills).
// Writes NORMALIZED p as bf16 [bh][i][j]. Row term 0.6*<a,s_i> dropped (softmax
// shift-invariance); no max pass (|e| <~ 25, fp32-exp safe).
__global__ __launch_bounds__(512) void escore_kernel(
    const float* __restrict__ Usrc, const unsigned* __restrict__ tP,
    const float* __restrict__ attn, unsigned short* __restrict__ pOut)
{
    __shared__ float s_lds[8][DD];     // 1KB
    __shared__ float wsum[8][8];

    const int tid = threadIdx.x;
    const int blk = blockIdx.x;
    const int it = blk & 63;           // 64 i-tiles of 8 rows
    const int bh = blk >> 6;           // 0..15

    const unsigned* tcol = tP + (size_t)bh * 16 * NN + tid;   // coalesced u32 columns
    const float* srcU = Usrc + (size_t)bh * NN * DD + (size_t)(it * 8) * DD;
    const float* aU   = attn + (bh & 3) * DD;                 // uniform -> s_load

    unsigned tpk[16];
    #pragma unroll
    for (int d2 = 0; d2 < 16; d2++) tpk[d2] = tcol[(size_t)d2 * NN];

    if (tid < 64) ((float4*)s_lds)[tid] = ((const float4*)srcU)[tid];
    __syncthreads();

    float At = 0.f, acc[8];
    #pragma unroll
    for (int r = 0; r < 8; r++) acc[r] = 0.f;

    #pragma unroll
    for (int dg = 0; dg < 8; dg++) {                // quad of d = [4dg, 4dg+4)
        const float a0 = aU[dg*4+0], a1 = aU[dg*4+1], a2 = aU[dg*4+2], a3 = aU[dg*4+3];
        const float t0 = bflo(tpk[dg*2]),   t1 = bfhi(tpk[dg*2]);
        const float t2 = bflo(tpk[dg*2+1]), t3 = bfhi(tpk[dg*2+1]);
        At = fmaf(a0, t0, fmaf(a1, t1, fmaf(a2, t2, fmaf(a3, t3, At))));
        #pragma unroll
        for (int r = 0; r < 8; r++) {
            float4 sv = *(float4*)&s_lds[r][dg * 4];
            acc[r] = fmaf(a0, fabsf(sv.x + t0), acc[r]);
            acc[r] = fmaf(a1, fabsf(sv.y + t1), acc[r]);
            acc[r] = fmaf(a2, fabsf(sv.z + t2), acc[r]);
            acc[r] = fmaf(a3, fabsf(sv.w + t3), acc[r]);
        }
    }

    const float cAt = 0.6f * SCALE * At;
    const int lane = tid & 63, w = tid >> 6;
    #pragma unroll
    for (int r = 0; r < 8; r++) {
        float p = __expf(fmaf(0.4f * SCALE, acc[r], cAt));
        acc[r] = p;
        float s = p;
        #pragma unroll
        for (int msk = 32; msk >= 1; msk >>= 1) s += __shfl_xor(s, msk);
        if (lane == 0) wsum[r][w] = s;
    }
    __syncthreads();

    unsigned short* pRow = pOut + ((size_t)bh * NN + it * 8) * NN + tid;
    #pragma unroll
    for (int r = 0; r < 8; r++) {
        float4 s0 = *(float4*)&wsum[r][0];
        float4 s1 = *(float4*)&wsum[r][4];
        float tot = ((s0.x + s0.y) + (s0.z + s0.w)) + ((s1.x + s1.y) + (s1.z + s1.w));
        pRow[(size_t)r * NN] = (unsigned short)f2bf(acc[r] / tot);
    }
}

// agg: batched MFMA GEMM  out[bh] = p[bh] (512x512) @ tT[bh] (32x512, k-contig)
// + residual + ReLU. One wave per 16-row M-tile; both n-tiles (32 d) per wave.
__global__ __launch_bounds__(256) void agg_kernel(
    const unsigned short* __restrict__ pM, const unsigned short* __restrict__ tT,
    const float* __restrict__ res, float* __restrict__ out)
{
    const int tid = threadIdx.x, l = tid & 63;
    const int gw = blockIdx.x * 4 + (tid >> 6);   // 0..511
    const int bh = gw >> 5, mt = gw & 31;
    const int b = bh >> 2, h = bh & 3;

    const unsigned short* pA = pM + (size_t)bh * NN * NN
                               + (size_t)(mt * 16 + (l & 15)) * NN + ((l >> 4) * 8);
    const unsigned short* pB = tT + (size_t)bh * DD * NN
                               + (size_t)(l & 15) * NN + ((l >> 4) * 8);

    f32x4 acc0 = {0.f, 0.f, 0.f, 0.f}, acc1 = {0.f, 0.f, 0.f, 0.f};
    #pragma unroll
    for (int kt = 0; kt < 16; kt++) {
        bf16x8 av = *(const bf16x8*)(pA + kt * 32);
        bf16x8 b0 = *(const bf16x8*)(pB + kt * 32);
        bf16x8 b1 = *(const bf16x8*)(pB + 16 * NN + kt * 32);
        acc0 = __builtin_amdgcn_mfma_f32_16x16x32_bf16(av, b0, acc0, 0, 0, 0);
        acc1 = __builtin_amdgcn_mfma_f32_16x16x32_bf16(av, b1, acc1, 0, 0, 0);
    }

    // C/D layout (m89): col = lane&15, row = (lane>>4)*4 + reg
    const int i0 = mt * 16 + (l >> 4) * 4;
    const int cc = l & 15;
    #pragma unroll
    for (int q = 0; q < 4; q++) {
        size_t row = (size_t)b * NN + i0 + q;
        size_t a0 = row * HID + h * DD + cc;
        out[a0]      = fmaxf(acc0[q] + res[a0],      0.f);
        out[a0 + 16] = fmaxf(acc1[q] + res[a0 + 16], 0.f);
    }
}

extern "C" void kernel_launch(void* const* d_in, const int* in_sizes, int n_in,
                              void* d_out, int out_size, void* d_ws, size_t ws_size,
                              hipStream_t stream) {
    const float* uf   = (const float*)d_in[0];
    const float* Wsrc = (const float*)d_in[1];
    const float* gsrc = (const float*)d_in[2];
    const float* bsrc = (const float*)d_in[3];
    const float* Wtgt = (const float*)d_in[4];
    const float* gtgt = (const float*)d_in[5];
    const float* btgt = (const float*)d_in[6];
    const float* attn = (const float*)d_in[7];
    const float* Wres = (const float*)d_in[8];
    const float* bres = (const float*)d_in[9];
    float* out = (float*)d_out;

    float* ws   = (float*)d_ws;
    float* Wt   = ws;                        // 49152 f
    float* Usrc = ws + 49152;                // 262144 f
    float* resb = Usrc + 262144;             // 262144 f
    unsigned short* tT = (unsigned short*)(resb + 262144);   // 262144 u16
    unsigned* tP = (unsigned*)(tT + 262144);                 // 131072 u32
    unsigned short* pM = (unsigned short*)(tP + 131072);     // 16*512*512 u16 = 8 MB

    pack_w<<<(FIN * NOUT + 255) / 256, 256, 0, stream>>>(Wsrc, Wtgt, Wres, Wt);
    proj_kernel<<<(BB * NN) / MT, NOUT, 0, stream>>>(uf, Wt, gsrc, bsrc, gtgt, btgt,
                                                     bres, Usrc, resb, tT, tP);
    escore_kernel<<<BB * HH * (NN / 8), 512, 0, stream>>>(Usrc, tP, attn, pM);
    agg_kernel<<<128, 256, 0, stream>>>(pM, tT, resb, out);
}